// Round 15
// baseline (783.350 us; speedup 1.0000x reference)
//
#include <hip/hip_runtime.h>

#define NN 50000
#define NE 1600000
#define C 64            // NOPEN == NUM_OUTPUT == 64
#define NIN 16
#define DTH 0.025f      // dt*H = (1.0/4)*0.1
#define ASC 16.0f       // adjacency weight scale
#define USC 64.0f       // u -> fp8 scale
#define SDIV 16384.0f   // ASC*ASC*USC
#define SLOT 128        // adjacency slots per node (P(overflow) ~ 1e-8, clamped)

// two-phase binned CSR build
#define NB2 256         // node-range bins (each owned by one phase-B block)
#define NPB 196         // nodes per bin (256*196 = 50176 >= NN)
#define CAP 16384       // stg capacity per bin (avg 12500, +34 sigma; clamped)
#define ABLK 1024       // phase-A blocks (also open-phase blocks)
#define EPB 1563        // edges per phase-A block (1024*1563 >= NE)
#define RND 2048        // edges per staging round (single round per block)
#define BINC 32         // LDS bin depth (avg fill ~12/round, Poisson tail ~1e-6)
#define GSTR 16         // gcur stride (64B) -> no atomic cache-line contention

typedef _Float16 f16x2 __attribute__((ext_vector_type(2)));
typedef float f32x2 __attribute__((ext_vector_type(2)));
union U32H2 { uint32_t u; f16x2 h; };

// s[p] broadcast via v_readlane -> SGPR fma operand (replaces ds_bpermute)
#define RL(x, l) __int_as_float(__builtin_amdgcn_readlane(__float_as_int(x), (l)))

// ---- setup: M2 = KN1*KN1^T, KM = KNc*KN1^T ; zero gcur ----
__global__ void k_setup(const float* __restrict__ KN1, const float* __restrict__ KNc,
                        float* __restrict__ M2s, float* __restrict__ KMs,
                        int* __restrict__ gcur) {
    if (threadIdx.x < NB2) gcur[threadIdx.x * GSTR] = 0;
    for (int idx = threadIdx.x; idx < C * C; idx += blockDim.x) {
        int p = idx >> 6, o = idx & 63;
        float s1 = 0.f, s2 = 0.f;
        for (int i = 0; i < C; i++) {
            s1 = fmaf(KN1[o * C + i], KN1[p * C + i], s1);
            s2 = fmaf(KNc[o * C + i], KN1[p * C + i], s2);
        }
        M2s[idx] = s1;
        KMs[idx] = s2;
    }
}

// pack 4 consecutive lanes' (USC-scaled) values into fp8x4, lanes lane%4==0 store
static __device__ __forceinline__ void store_u8(uint32_t* __restrict__ u8, int n, int lane, float su) {
    float v1 = __shfl_down(su, 1, 64);
    float v2 = __shfl_down(su, 2, 64);
    float v3 = __shfl_down(su, 3, 64);
    if ((lane & 3) == 0) {
        int p0 = __builtin_amdgcn_cvt_pk_fp8_f32(su, v1, 0, false);
        int p1 = __builtin_amdgcn_cvt_pk_fp8_f32(v2, v3, p0, true);
        u8[n * 16 + (lane >> 2)] = (uint32_t)p1;
    }
}

// ---- fused: phase-A binned edge scatter, then opening matvecs as epilogue ----
// open phase stages xn tiles through LDS (coalesced + reg-prefetched) to kill
// the per-wave wave-uniform global-load stalls.
__launch_bounds__(512)
__global__ void k_binA_open(const int* __restrict__ iInd, const int* __restrict__ jInd,
                            int* __restrict__ gcur, uint32_t* __restrict__ stg,
                            const float* __restrict__ xn, const float* __restrict__ K1,
                            const float* __restrict__ KN1, const float* __restrict__ KNc,
                            _Float16* __restrict__ u0, uint32_t* __restrict__ u8,
                            float* __restrict__ co) {
    __shared__ __align__(16) char smem[36864];
    __shared__ int bcnt[NB2];
    __shared__ int gbase[NB2];
    __shared__ float sxn[NIN][17];      // staged xn tile: 16 features x 16 nodes (+pad)
    uint32_t (*bins)[BINC] = (uint32_t(*)[BINC])smem;
    int tid = threadIdx.x;
    int eBeg = blockIdx.x * EPB;
    int eEnd = eBeg + EPB; if (eEnd > NE) eEnd = NE;
    for (int rb = eBeg; rb < eEnd; rb += RND) {
        for (int b = tid; b < NB2; b += 512) bcnt[b] = 0;
        __syncthreads();
        int rEnd = rb + RND; if (rEnd > eEnd) rEnd = eEnd;
        for (int e = rb + tid; e < rEnd; e += 512) {
            int i = __builtin_nontemporal_load(&iInd[e]);
            int j = __builtin_nontemporal_load(&jInd[e]);
            {   // i-side: target=i, sign 0
                int b = (unsigned)i / NPB;
                uint32_t ent = ((unsigned)(i - b * NPB) << 17) | (unsigned)j;
                int pos = atomicAdd(&bcnt[b], 1);
                if (pos < BINC) bins[b][pos] = ent;
                else { int gp = atomicAdd(&gcur[b * GSTR], 1);
                       if (gp < CAP) stg[(size_t)b * CAP + gp] = ent; }
            }
            {   // j-side: target=j, sign 1
                int b = (unsigned)j / NPB;
                uint32_t ent = ((unsigned)(j - b * NPB) << 17) | 0x10000u | (unsigned)i;
                int pos = atomicAdd(&bcnt[b], 1);
                if (pos < BINC) bins[b][pos] = ent;
                else { int gp = atomicAdd(&gcur[b * GSTR], 1);
                       if (gp < CAP) stg[(size_t)b * CAP + gp] = ent; }
            }
        }
        __syncthreads();
        if (tid < NB2) {   // reserve per-bin ranges
            int c = bcnt[tid]; if (c > BINC) c = BINC;
            gbase[tid] = (c > 0) ? atomicAdd(&gcur[tid * GSTR], c) : 0;
        }
        __syncthreads();
        // coalesced flush
        for (int idx = tid; idx < NB2 * BINC; idx += 512) {
            int b = idx >> 5, k = idx & (BINC - 1);
            int c = bcnt[b]; if (c > BINC) c = BINC;
            if (k < c) {
                int pos = gbase[b] + k;
                if (pos < CAP) stg[(size_t)b * CAP + pos] = bins[b][k];
            }
        }
        __syncthreads();   // also fences LDS before the union flips to open phase
    }
    // ---- open phase: x = relu(K1*xn); u0 = KN1*x (f16+fp8); co = KNc*x ----
    float* sK1 = (float*)smem;          // [i][o], 1024 floats
    float* sU  = sK1 + NIN * C;         // swizzled KN1, 4096 floats
    float* sC  = sU + C * C;            // swizzled KNc, 4096 floats
    for (int idx = tid; idx < NIN * C; idx += 512) {
        int i = idx >> 6, o = idx & 63;
        sK1[idx] = K1[o * NIN + i];
    }
    for (int idx = tid; idx < C * C; idx += 512) {
        int o = idx >> 6, p = idx & 63;
        int sw = (o << 6) | (p ^ ((o & 7) << 2));
        sU[sw] = KN1[idx];
        sC[sw] = KNc[idx];
    }
    int wv = tid >> 6, lane = tid & 63;
    int mb = lane << 6, lx = (lane & 7) << 2;
    int w2 = wv * 2;
    // per-block lockstep iterations; all waves in a block share trip count:
    // it valid iff blockIdx*8+7+it*8192 < 25000 -> nit = 3 + (blockIdx < 53)
    int nit = 3 + (blockIdx.x < 53 ? 1 : 0);
    int fi = tid >> 4, ft = tid & 15;   // feature row, node col (tid < 256)
    float vpre = 0.f;
    if (tid < 256) vpre = xn[fi * NN + blockIdx.x * 16 + ft];
    for (int it = 0; it < nit; it++) {
        __syncthreads();                 // prior iteration's sxn reads done
        if (tid < 256) sxn[fi][ft] = vpre;
        __syncthreads();                 // tile visible
        if (it + 1 < nit && tid < 256)   // prefetch next tile (hidden under compute)
            vpre = xn[fi * NN + blockIdx.x * 16 + (it + 1) * 16384 + ft];
        int pr = blockIdx.x * 8 + wv + it * 8192;
        int nA = pr * 2, nB = nA + 1;
        float xA = 0.f, xB = 0.f;
#pragma unroll
        for (int i = 0; i < NIN; i++) {
            float k1 = sK1[i * C + lane];
            xA = fmaf(k1, sxn[i][w2], xA);
            xB = fmaf(k1, sxn[i][w2 + 1], xB);
        }
        xA = fmaxf(xA, 0.f); xB = fmaxf(xB, 0.f);
        float uA0 = 0.f, uA1 = 0.f, uB0 = 0.f, uB1 = 0.f;
        float cA0 = 0.f, cA1 = 0.f, cB0 = 0.f, cB1 = 0.f;
#pragma unroll
        for (int p0 = 0; p0 < C; p0 += 4) {
            const float4 mu = *(const float4*)&sU[mb + (p0 ^ lx)];
            const float4 mc = *(const float4*)&sC[mb + (p0 ^ lx)];
            float a0 = RL(xA, p0 + 0), a1 = RL(xA, p0 + 1);
            float a2 = RL(xA, p0 + 2), a3 = RL(xA, p0 + 3);
            float b0 = RL(xB, p0 + 0), b1 = RL(xB, p0 + 1);
            float b2 = RL(xB, p0 + 2), b3 = RL(xB, p0 + 3);
            uA0 = fmaf(mu.x, a0, uA0); uA1 = fmaf(mu.y, a1, uA1);
            uA0 = fmaf(mu.z, a2, uA0); uA1 = fmaf(mu.w, a3, uA1);
            uB0 = fmaf(mu.x, b0, uB0); uB1 = fmaf(mu.y, b1, uB1);
            uB0 = fmaf(mu.z, b2, uB0); uB1 = fmaf(mu.w, b3, uB1);
            cA0 = fmaf(mc.x, a0, cA0); cA1 = fmaf(mc.y, a1, cA1);
            cA0 = fmaf(mc.z, a2, cA0); cA1 = fmaf(mc.w, a3, cA1);
            cB0 = fmaf(mc.x, b0, cB0); cB1 = fmaf(mc.y, b1, cB1);
            cB0 = fmaf(mc.z, b2, cB0); cB1 = fmaf(mc.w, b3, cB1);
        }
        float uA = uA0 + uA1, uB = uB0 + uB1;
        u0[(size_t)nA * C + lane] = (_Float16)uA;
        u0[(size_t)nB * C + lane] = (_Float16)uB;
        store_u8(u8, nA, lane, uA * USC);
        store_u8(u8, nB, lane, uB * USC);
        co[(size_t)nA * C + lane] = cA0 + cA1;
        co[(size_t)nB * C + lane] = cB0 + cB1;
    }
}

// ---- phase B: per-bin slot assignment into 100KB LDS image, coalesced copy-out ----
#define LADJ (NPB * SLOT)   // 25088 dwords = 100352 B LDS adjacency image
__launch_bounds__(1024)
__global__ void k_binB(const int* __restrict__ gcur, const uint32_t* __restrict__ stg,
                       unsigned* __restrict__ pk, float* __restrict__ dinv,
                       uint32_t* __restrict__ adjp) {
    __shared__ unsigned lcnt[NPB];   // low16 = slot count, high16 = j-side count
    __shared__ uint32_t ladj[LADJ];
    int b = blockIdx.x, tid = threadIdx.x;
    if (tid < NPB) lcnt[tid] = 0;
    __syncthreads();
    int cnt = gcur[b * GSTR]; if (cnt > CAP) cnt = CAP;
    int n0 = b * NPB;
    for (int k = tid; k < cnt; k += 1024) {
        uint32_t ent = stg[(size_t)b * CAP + k];
        int tl = (int)(ent >> 17);
        unsigned sign = (ent >> 16) & 1u;
        unsigned other = ent & 0xFFFFu;
        unsigned ret = atomicAdd(&lcnt[tl], 1u + (sign << 16));
        unsigned slot = ret & 0xFFFFu;
        if (slot < SLOT) ladj[(tl << 7) + slot] = other | (sign << 31);
    }
    __syncthreads();
    if (tid < NPB) {
        int n = n0 + tid;
        if (n < NN) {
            unsigned v = lcnt[tid];
            unsigned c = v & 0xFFFFu; if (c > SLOT) c = SLOT;
            unsigned deg = (v >> 16) + 1u;   // j-count + self loop
            pk[n] = (deg << 16) | c;
            dinv[n] = 1.0f / sqrtf((float)deg);
        }
    }
    // coalesced copy-out (slots >= cnt are garbage; k_weight zeroes pads)
    int nval = NN - n0; if (nval > NPB) nval = NPB; if (nval < 0) nval = 0;
    int totv = (nval << 7) >> 2;   // uint4 count
    uint4* gdst = (uint4*)(adjp + ((size_t)n0 << 7));
    const uint4* lsrc = (const uint4*)ladj;
    for (int v = tid; v < totv; v += 1024) gdst[v] = lsrc[v];
}

// ---- weight pass (uint4, 4 slots/thread): entry -> other | f16(sign*0.5*a^2)<<16 ----
// pads in [cnt,pad) zeroed; gather uses acc += |w|*d + w*|d| (== a*relu(a*d)).
__launch_bounds__(256)
__global__ void k_weight(const unsigned* __restrict__ pk, const float* __restrict__ dinv,
                         uint32_t* __restrict__ adjp) {
    int idx = blockIdx.x * 256 + threadIdx.x;   // NN*SLOT/4 threads
    int n = idx >> 5, p4 = (idx & 31) << 2;
    int cnt = (int)(pk[n] & 0xFFFFu); if (cnt > SLOT) cnt = SLOT;
    int pad = (cnt + 31) & ~31;
    if (p4 >= pad) return;
    size_t base = ((size_t)n << 7) + p4;
    uint4 e = *(const uint4*)&adjp[base];
    float dn = ASC * dinv[n];
    uint32_t r[4] = {e.x, e.y, e.z, e.w};
    uint32_t w[4];
#pragma unroll
    for (int k = 0; k < 4; k++) {
        if (p4 + k < cnt) {
            int other = (int)(r[k] & 0xFFFFu);
            float a = dn * dinv[other];
            float wv = 0.5f * a * a;
            if (r[k] >> 31) wv = -wv;
            U32H2 t; t.u = (unsigned)other; t.h.y = (_Float16)wv;
            w[k] = t.u;
        } else {
            w[k] = 0u;                           // weight 0 -> contributes nothing
        }
    }
    uint4 o; o.x = w[0]; o.y = w[1]; o.z = w[2]; o.w = w[3];
    *(uint4*)&adjp[base] = o;
}

// acc += |w|*d + w*|d|  (== a*relu(a*d)); abs() are free VOP3 source modifiers
#define ACCR(WW, QQ, A0, A1, A2, A3, U0, U1, U2, U3) {                        \
    U32H2 aw; aw.u = (WW);                                                    \
    float w_ = (float)aw.h.y;                                                 \
    f32x2 lo_ = __builtin_amdgcn_cvt_pk_f32_fp8((int)(QQ), false);            \
    f32x2 hi_ = __builtin_amdgcn_cvt_pk_f32_fp8((int)(QQ), true);             \
    float d0_ = (U0) - lo_.x, d1_ = (U1) - lo_.y;                             \
    float d2_ = (U2) - hi_.x, d3_ = (U3) - hi_.y;                             \
    A0 = fmaf(w_, __builtin_fabsf(d0_), fmaf(__builtin_fabsf(w_), d0_, A0));  \
    A1 = fmaf(w_, __builtin_fabsf(d1_), fmaf(__builtin_fabsf(w_), d1_, A1));  \
    A2 = fmaf(w_, __builtin_fabsf(d2_), fmaf(__builtin_fabsf(w_), d2_, A2));  \
    A3 = fmaf(w_, __builtin_fabsf(d3_), fmaf(__builtin_fabsf(w_), d3_, A3));  \
}

// ---- two-node interleaved gather core, 64-slot iterations ----
// both 32-chunks' adj loads issued first, then both chunks' u8 gathers, then math:
// doubles in-flight loads per wave (L2-latency-bound -> MLP is the lever).
// accumulation order per node unchanged vs 32-step loop (c0 then c0+32) -> bit-identical.
#define GATHER2_BODY(PKA, ADJP, U8R)                                          \
    uint32_t unqA = (U8R)[nA * 16 + li];                                      \
    uint32_t unqB = (U8R)[nB * 16 + li];                                      \
    f32x2 alo = __builtin_amdgcn_cvt_pk_f32_fp8((int)unqA, false);            \
    f32x2 ahi = __builtin_amdgcn_cvt_pk_f32_fp8((int)unqA, true);             \
    f32x2 blo = __builtin_amdgcn_cvt_pk_f32_fp8((int)unqB, false);            \
    f32x2 bhi = __builtin_amdgcn_cvt_pk_f32_fp8((int)unqB, true);             \
    float uA0 = alo.x, uA1 = alo.y, uA2 = ahi.x, uA3 = ahi.y;                 \
    float uB0 = blo.x, uB1 = blo.y, uB2 = bhi.x, uB3 = bhi.y;                 \
    uint2 pk2_ = *(const uint2*)&(PKA)[nA];                                   \
    int degA = (int)(pk2_.x & 0xFFFFu); if (degA > SLOT) degA = SLOT;         \
    int degB = (int)(pk2_.y & 0xFFFFu); if (degB > SLOT) degB = SLOT;         \
    int padA = (degA + 31) & ~31, padB = (degB + 31) & ~31;                   \
    int baseA = nA << 7, baseB = nB << 7;                                     \
    int maxPad = padA > padB ? padA : padB;                                   \
    float aA0 = 0.f, aA1 = 0.f, aA2 = 0.f, aA3 = 0.f;                         \
    float aB0 = 0.f, aB1 = 0.f, aB2 = 0.f, aB3 = 0.f;                         \
    for (int c0 = 0; c0 < maxPad; c0 += 64) {                                 \
        uint32_t wA1[8], wA2[8], wB1[8], wB2[8];                              \
        uint32_t qA1[8], qA2[8], qB1[8], qB2[8];                              \
        bool dA1 = c0 < padA, dA2 = c0 + 32 < padA;                           \
        bool dB1 = c0 < padB, dB2 = c0 + 32 < padB;                           \
        if (dA1) {                                                            \
            _Pragma("unroll")                                                 \
            for (int r = 0; r < 8; r++) wA1[r] = (ADJP)[baseA + c0 + r * 4 + g]; \
        }                                                                     \
        if (dA2) {                                                            \
            _Pragma("unroll")                                                 \
            for (int r = 0; r < 8; r++) wA2[r] = (ADJP)[baseA + c0 + 32 + r * 4 + g]; \
        }                                                                     \
        if (dB1) {                                                            \
            _Pragma("unroll")                                                 \
            for (int r = 0; r < 8; r++) wB1[r] = (ADJP)[baseB + c0 + r * 4 + g]; \
        }                                                                     \
        if (dB2) {                                                            \
            _Pragma("unroll")                                                 \
            for (int r = 0; r < 8; r++) wB2[r] = (ADJP)[baseB + c0 + 32 + r * 4 + g]; \
        }                                                                     \
        if (dA1) {                                                            \
            _Pragma("unroll")                                                 \
            for (int r = 0; r < 8; r++) qA1[r] = (U8R)[(wA1[r] & 0xFFFFu) * 16 + li]; \
        }                                                                     \
        if (dA2) {                                                            \
            _Pragma("unroll")                                                 \
            for (int r = 0; r < 8; r++) qA2[r] = (U8R)[(wA2[r] & 0xFFFFu) * 16 + li]; \
        }                                                                     \
        if (dB1) {                                                            \
            _Pragma("unroll")                                                 \
            for (int r = 0; r < 8; r++) qB1[r] = (U8R)[(wB1[r] & 0xFFFFu) * 16 + li]; \
        }                                                                     \
        if (dB2) {                                                            \
            _Pragma("unroll")                                                 \
            for (int r = 0; r < 8; r++) qB2[r] = (U8R)[(wB2[r] & 0xFFFFu) * 16 + li]; \
        }                                                                     \
        if (dA1) {                                                            \
            _Pragma("unroll")                                                 \
            for (int r = 0; r < 8; r++) ACCR(wA1[r], qA1[r], aA0, aA1, aA2, aA3, uA0, uA1, uA2, uA3) \
        }                                                                     \
        if (dA2) {                                                            \
            _Pragma("unroll")                                                 \
            for (int r = 0; r < 8; r++) ACCR(wA2[r], qA2[r], aA0, aA1, aA2, aA3, uA0, uA1, uA2, uA3) \
        }                                                                     \
        if (dB1) {                                                            \
            _Pragma("unroll")                                                 \
            for (int r = 0; r < 8; r++) ACCR(wB1[r], qB1[r], aB0, aB1, aB2, aB3, uB0, uB1, uB2, uB3) \
        }                                                                     \
        if (dB2) {                                                            \
            _Pragma("unroll")                                                 \
            for (int r = 0; r < 8; r++) ACCR(wB2[r], qB2[r], aB0, aB1, aB2, aB3, uB0, uB1, uB2, uB3) \
        }                                                                     \
    }                                                                         \
    aA0 += __shfl_xor(aA0, 16, 64); aA0 += __shfl_xor(aA0, 32, 64);           \
    aA1 += __shfl_xor(aA1, 16, 64); aA1 += __shfl_xor(aA1, 32, 64);           \
    aA2 += __shfl_xor(aA2, 16, 64); aA2 += __shfl_xor(aA2, 32, 64);           \
    aA3 += __shfl_xor(aA3, 16, 64); aA3 += __shfl_xor(aA3, 32, 64);           \
    aB0 += __shfl_xor(aB0, 16, 64); aB0 += __shfl_xor(aB0, 32, 64);           \
    aB1 += __shfl_xor(aB1, 16, 64); aB1 += __shfl_xor(aB1, 32, 64);           \
    aB2 += __shfl_xor(aB2, 16, 64); aB2 += __shfl_xor(aB2, 32, 64);           \
    aB3 += __shfl_xor(aB3, 16, 64); aB3 += __shfl_xor(aB3, 32, 64);           \
    float rA0 = __shfl(aA0, lane >> 2, 64), rA1 = __shfl(aA1, lane >> 2, 64); \
    float rA2 = __shfl(aA2, lane >> 2, 64), rA3 = __shfl(aA3, lane >> 2, 64); \
    float rB0 = __shfl(aB0, lane >> 2, 64), rB1 = __shfl(aB1, lane >> 2, 64); \
    float rB2 = __shfl(aB2, lane >> 2, 64), rB3 = __shfl(aB3, lane >> 2, 64); \
    float sA_lane = (lane & 2) ? ((lane & 1) ? rA3 : rA2)                     \
                               : ((lane & 1) ? rA1 : rA0);                    \
    float sB_lane = (lane & 2) ? ((lane & 1) ? rB3 : rB2)                     \
                               : ((lane & 1) ? rB1 : rB0);

// transposed + XOR-swizzled M staging: sMt[(c<<6) | (p ^ ((c&7)<<2))] = M[p][c]
#define STAGE_MT(SMT, SRC) {                                                  \
    for (int idx = threadIdx.x; idx < C * C; idx += 256) {                    \
        int p_ = idx >> 6, c_ = idx & 63;                                     \
        (SMT)[(c_ << 6) | (p_ ^ ((c_ & 7) << 2))] = (SRC)[idx];               \
    }                                                                         \
}

// du[lane] = sum_p M[p][lane] * s[p] for 2 nodes; 16 ds_read_b128 + 64 RL + 64 fma per node
#define MATVEC2(SMT, SAV, SBV, DUA, DUB) {                                    \
    float mA0_ = 0.f, mA1_ = 0.f, mB0_ = 0.f, mB1_ = 0.f;                     \
    int mb_ = (lane << 6), lx_ = (lane & 7) << 2;                             \
    _Pragma("unroll")                                                         \
    for (int p0 = 0; p0 < 64; p0 += 4) {                                      \
        const float4 mv = *(const float4*)&(SMT)[mb_ + (p0 ^ lx_)];           \
        mA0_ = fmaf(mv.x, RL(SAV, p0 + 0), mA0_);                             \
        mA1_ = fmaf(mv.y, RL(SAV, p0 + 1), mA1_);                             \
        mA0_ = fmaf(mv.z, RL(SAV, p0 + 2), mA0_);                             \
        mA1_ = fmaf(mv.w, RL(SAV, p0 + 3), mA1_);                             \
        mB0_ = fmaf(mv.x, RL(SBV, p0 + 0), mB0_);                             \
        mB1_ = fmaf(mv.y, RL(SBV, p0 + 1), mB1_);                             \
        mB0_ = fmaf(mv.z, RL(SBV, p0 + 2), mB0_);                             \
        mB1_ = fmaf(mv.w, RL(SBV, p0 + 3), mB1_);                             \
    }                                                                         \
    DUA = mA0_ + mA1_; DUB = mB0_ + mB1_;                                     \
}

// ---- layers 0..2 fused: s = gather; unext = ucur - c*M2*s (f16+fp8); sacc (+)= s ----
__launch_bounds__(256, 5)
__global__ void k_gather_upd(const unsigned* __restrict__ pk, const uint32_t* __restrict__ adjp,
                             const uint32_t* __restrict__ u8r, const _Float16* __restrict__ ucur,
                             const float* __restrict__ M2s, float* __restrict__ sacc,
                             _Float16* __restrict__ unext, uint32_t* __restrict__ u8w, int beta) {
    __shared__ float sMt[C * C];
    STAGE_MT(sMt, M2s)
    __syncthreads();
    int wv = threadIdx.x >> 6, lane = threadIdx.x & 63;
    int g = lane >> 4, li = lane & 15;
    int nA = (blockIdx.x * 4 + wv) * 2;   // 6250 blocks * 4 waves * 2 nodes = 50000
    int nB = nA + 1;
    GATHER2_BODY(pk, adjp, u8r)
    float duA, duB;
    MATVEC2(sMt, sA_lane, sB_lane, duA, duB)
    float unewA = (float)ucur[(size_t)nA * C + lane] - (DTH / SDIV) * duA;
    float unewB = (float)ucur[(size_t)nB * C + lane] - (DTH / SDIV) * duB;
    unext[(size_t)nA * C + lane] = (_Float16)unewA;
    unext[(size_t)nB * C + lane] = (_Float16)unewB;
    store_u8(u8w, nA, lane, unewA * USC);
    store_u8(u8w, nB, lane, unewB * USC);
    size_t ixA = (size_t)nA * C + lane, ixB = (size_t)nB * C + lane;
    sacc[ixA] = beta ? (sacc[ixA] + sA_lane) : sA_lane;
    sacc[ixB] = beta ? (sacc[ixB] + sB_lane) : sB_lane;
}

// ---- final layer fused: stot = sacc + s; out = log_softmax(co - c*KM*stot) ----
__launch_bounds__(256, 5)
__global__ void k_gather_close(const unsigned* __restrict__ pk, const uint32_t* __restrict__ adjp,
                               const uint32_t* __restrict__ u8r, const float* __restrict__ KMs,
                               const float* __restrict__ sacc, const float* __restrict__ co,
                               float* __restrict__ out) {
    __shared__ float sKMt[C * C];
    STAGE_MT(sKMt, KMs)
    __syncthreads();
    int wv = threadIdx.x >> 6, lane = threadIdx.x & 63;
    int g = lane >> 4, li = lane & 15;
    int nA = (blockIdx.x * 4 + wv) * 2;
    int nB = nA + 1;
    GATHER2_BODY(pk, adjp, u8r)
    float stotA = sA_lane + sacc[(size_t)nA * C + lane];
    float stotB = sB_lane + sacc[(size_t)nB * C + lane];
    float dxA, dxB;
    MATVEC2(sKMt, stotA, stotB, dxA, dxB)
    float oA = co[(size_t)nA * C + lane] - (DTH / SDIV) * dxA;
    float oB = co[(size_t)nB * C + lane] - (DTH / SDIV) * dxB;
    float mA = oA, mB = oB;
#pragma unroll
    for (int off2 = 32; off2; off2 >>= 1) {
        mA = fmaxf(mA, __shfl_xor(mA, off2, 64));
        mB = fmaxf(mB, __shfl_xor(mB, off2, 64));
    }
    float sumA = expf(oA - mA), sumB = expf(oB - mB);
#pragma unroll
    for (int off2 = 32; off2; off2 >>= 1) {
        sumA += __shfl_xor(sumA, off2, 64);
        sumB += __shfl_xor(sumB, off2, 64);
    }
    out[(size_t)nA * C + lane] = oA - mA - logf(sumA);
    out[(size_t)nB * C + lane] = oB - mB - logf(sumB);
}

extern "C" void kernel_launch(void* const* d_in, const int* in_sizes, int n_in,
                              void* d_out, int out_size, void* d_ws, size_t ws_size,
                              hipStream_t stream) {
    (void)in_sizes; (void)n_in; (void)out_size; (void)ws_size;
    const float* xn   = (const float*)d_in[0];
    const int* iInd   = (const int*)d_in[1];
    const int* jInd   = (const int*)d_in[2];
    // d_in[3] = n_nodes scalar (fixed 50000)
    const float* K1   = (const float*)d_in[4];
    const float* KN1  = (const float*)d_in[5];
    const float* KNc  = (const float*)d_in[6];
    float* out = (float*)d_out;

    char* base = (char*)d_ws;
    size_t off = 0;
    auto alloc = [&](size_t bytes) { char* p = base + off; off = (off + bytes + 255) & ~(size_t)255; return p; };
    float* M2s  = (float*)alloc(C * C * 4);
    float* KMs  = (float*)alloc(C * C * 4);
    int* gcur   = (int*)alloc(NB2 * GSTR * 4);
    unsigned* pk = (unsigned*)alloc(NN * 4);
    float* dinv = (float*)alloc(NN * 4);
    float* co   = (float*)alloc((size_t)NN * C * 4);       // 12.8 MB
    float* sacc = (float*)alloc((size_t)NN * C * 4);       // 12.8 MB
    _Float16* ua = (_Float16*)alloc((size_t)NN * C * 2);   // 6.4 MB
    _Float16* ub = (_Float16*)alloc((size_t)NN * C * 2);   // 6.4 MB
    uint32_t* u8a = (uint32_t*)alloc((size_t)NN * 16 * 4); // 3.2 MB
    uint32_t* u8b = (uint32_t*)alloc((size_t)NN * 16 * 4); // 3.2 MB
    uint32_t* stg = (uint32_t*)alloc((size_t)NB2 * CAP * 4);  // 16.8 MB
    uint32_t* adjp = (uint32_t*)alloc((size_t)NN * SLOT * 4); // 25.6 MB

    // prolog: CSR build with opening matvecs fused into phase A
    k_setup<<<1, 256, 0, stream>>>(KN1, KNc, M2s, KMs, gcur);
    k_binA_open<<<ABLK, 512, 0, stream>>>(iInd, jInd, gcur, stg, xn, K1, KN1, KNc, ua, u8a, co);
    k_binB<<<NB2, 1024, 0, stream>>>(gcur, stg, pk, dinv, adjp);
    k_weight<<<(NN * SLOT / 4) / 256, 256, 0, stream>>>(pk, dinv, adjp);

    const int GB = NN / 8;    // 6250 blocks, two nodes per wave
    k_gather_upd<<<GB, 256, 0, stream>>>(pk, adjp, u8a, ua, M2s, sacc, ub, u8b, 0);
    k_gather_upd<<<GB, 256, 0, stream>>>(pk, adjp, u8b, ub, M2s, sacc, ua, u8a, 1);
    k_gather_upd<<<GB, 256, 0, stream>>>(pk, adjp, u8a, ua, M2s, sacc, ub, u8b, 1);
    k_gather_close<<<GB, 256, 0, stream>>>(pk, adjp, u8b, KMs, sacc, co, out);
}

// Round 16
// 457.894 us; speedup vs baseline: 1.7108x; 1.7108x over previous
//
#include <hip/hip_runtime.h>

#define NN 50000
#define NE 1600000
#define C 64            // NOPEN == NUM_OUTPUT == 64
#define NIN 16
#define DTH 0.025f      // dt*H = (1.0/4)*0.1
#define ASC 16.0f       // adjacency weight scale
#define USC 64.0f       // u -> fp8 scale
#define SDIV 16384.0f   // ASC*ASC*USC
#define SLOT 128        // adjacency slots per node (P(overflow) ~ 1e-8, clamped)

// two-phase binned CSR build
#define NB2 256         // node-range bins (each owned by one phase-B block)
#define NPB 196         // nodes per bin (256*196 = 50176 >= NN)
#define CAP 16384       // stg capacity per bin (avg 12500, +34 sigma; clamped)
#define ABLK 1024       // phase-A blocks (also open-phase blocks)
#define EPB 1563        // edges per phase-A block (1024*1563 >= NE)
#define RND 2048        // edges per staging round (single round per block)
#define BINC 32         // LDS bin depth (avg fill ~12/round, Poisson tail ~1e-6)
#define GSTR 16         // gcur stride (64B) -> no atomic cache-line contention

typedef _Float16 f16x2 __attribute__((ext_vector_type(2)));
typedef float f32x2 __attribute__((ext_vector_type(2)));
union U32H2 { uint32_t u; f16x2 h; };

// s[p] broadcast via v_readlane -> SGPR fma operand (replaces ds_bpermute)
#define RL(x, l) __int_as_float(__builtin_amdgcn_readlane(__float_as_int(x), (l)))

// ---- setup: M2 = KN1*KN1^T, KM = KNc*KN1^T ; zero gcur ----
__global__ void k_setup(const float* __restrict__ KN1, const float* __restrict__ KNc,
                        float* __restrict__ M2s, float* __restrict__ KMs,
                        int* __restrict__ gcur) {
    if (threadIdx.x < NB2) gcur[threadIdx.x * GSTR] = 0;
    for (int idx = threadIdx.x; idx < C * C; idx += blockDim.x) {
        int p = idx >> 6, o = idx & 63;
        float s1 = 0.f, s2 = 0.f;
        for (int i = 0; i < C; i++) {
            s1 = fmaf(KN1[o * C + i], KN1[p * C + i], s1);
            s2 = fmaf(KNc[o * C + i], KN1[p * C + i], s2);
        }
        M2s[idx] = s1;
        KMs[idx] = s2;
    }
}

// pack 4 consecutive lanes' (USC-scaled) values into fp8x4, lanes lane%4==0 store
static __device__ __forceinline__ void store_u8(uint32_t* __restrict__ u8, int n, int lane, float su) {
    float v1 = __shfl_down(su, 1, 64);
    float v2 = __shfl_down(su, 2, 64);
    float v3 = __shfl_down(su, 3, 64);
    if ((lane & 3) == 0) {
        int p0 = __builtin_amdgcn_cvt_pk_fp8_f32(su, v1, 0, false);
        int p1 = __builtin_amdgcn_cvt_pk_fp8_f32(v2, v3, p0, true);
        u8[n * 16 + (lane >> 2)] = (uint32_t)p1;
    }
}

// ---- fused: phase-A binned edge scatter, then opening matvecs as epilogue ----
// open phase stages xn tiles through LDS (coalesced + reg-prefetched) to kill
// the per-wave wave-uniform global-load stalls.
__launch_bounds__(512)
__global__ void k_binA_open(const int* __restrict__ iInd, const int* __restrict__ jInd,
                            int* __restrict__ gcur, uint32_t* __restrict__ stg,
                            const float* __restrict__ xn, const float* __restrict__ K1,
                            const float* __restrict__ KN1, const float* __restrict__ KNc,
                            _Float16* __restrict__ u0, uint32_t* __restrict__ u8,
                            float* __restrict__ co) {
    __shared__ __align__(16) char smem[36864];
    __shared__ int bcnt[NB2];
    __shared__ int gbase[NB2];
    __shared__ float sxn[NIN][17];      // staged xn tile: 16 features x 16 nodes (+pad)
    uint32_t (*bins)[BINC] = (uint32_t(*)[BINC])smem;
    int tid = threadIdx.x;
    int eBeg = blockIdx.x * EPB;
    int eEnd = eBeg + EPB; if (eEnd > NE) eEnd = NE;
    for (int rb = eBeg; rb < eEnd; rb += RND) {
        for (int b = tid; b < NB2; b += 512) bcnt[b] = 0;
        __syncthreads();
        int rEnd = rb + RND; if (rEnd > eEnd) rEnd = eEnd;
        for (int e = rb + tid; e < rEnd; e += 512) {
            int i = __builtin_nontemporal_load(&iInd[e]);
            int j = __builtin_nontemporal_load(&jInd[e]);
            {   // i-side: target=i, sign 0
                int b = (unsigned)i / NPB;
                uint32_t ent = ((unsigned)(i - b * NPB) << 17) | (unsigned)j;
                int pos = atomicAdd(&bcnt[b], 1);
                if (pos < BINC) bins[b][pos] = ent;
                else { int gp = atomicAdd(&gcur[b * GSTR], 1);
                       if (gp < CAP) stg[(size_t)b * CAP + gp] = ent; }
            }
            {   // j-side: target=j, sign 1
                int b = (unsigned)j / NPB;
                uint32_t ent = ((unsigned)(j - b * NPB) << 17) | 0x10000u | (unsigned)i;
                int pos = atomicAdd(&bcnt[b], 1);
                if (pos < BINC) bins[b][pos] = ent;
                else { int gp = atomicAdd(&gcur[b * GSTR], 1);
                       if (gp < CAP) stg[(size_t)b * CAP + gp] = ent; }
            }
        }
        __syncthreads();
        if (tid < NB2) {   // reserve per-bin ranges
            int c = bcnt[tid]; if (c > BINC) c = BINC;
            gbase[tid] = (c > 0) ? atomicAdd(&gcur[tid * GSTR], c) : 0;
        }
        __syncthreads();
        // coalesced flush
        for (int idx = tid; idx < NB2 * BINC; idx += 512) {
            int b = idx >> 5, k = idx & (BINC - 1);
            int c = bcnt[b]; if (c > BINC) c = BINC;
            if (k < c) {
                int pos = gbase[b] + k;
                if (pos < CAP) stg[(size_t)b * CAP + pos] = bins[b][k];
            }
        }
        __syncthreads();   // also fences LDS before the union flips to open phase
    }
    // ---- open phase: x = relu(K1*xn); u0 = KN1*x (f16+fp8); co = KNc*x ----
    float* sK1 = (float*)smem;          // [i][o], 1024 floats
    float* sU  = sK1 + NIN * C;         // swizzled KN1, 4096 floats
    float* sC  = sU + C * C;            // swizzled KNc, 4096 floats
    for (int idx = tid; idx < NIN * C; idx += 512) {
        int i = idx >> 6, o = idx & 63;
        sK1[idx] = K1[o * NIN + i];
    }
    for (int idx = tid; idx < C * C; idx += 512) {
        int o = idx >> 6, p = idx & 63;
        int sw = (o << 6) | (p ^ ((o & 7) << 2));
        sU[sw] = KN1[idx];
        sC[sw] = KNc[idx];
    }
    int wv = tid >> 6, lane = tid & 63;
    int mb = lane << 6, lx = (lane & 7) << 2;
    int w2 = wv * 2;
    // per-block lockstep iterations; all waves in a block share trip count:
    // it valid iff blockIdx*8+7+it*8192 < 25000 -> nit = 3 + (blockIdx < 53)
    int nit = 3 + (blockIdx.x < 53 ? 1 : 0);
    int fi = tid >> 4, ft = tid & 15;   // feature row, node col (tid < 256)
    float vpre = 0.f;
    if (tid < 256) vpre = xn[fi * NN + blockIdx.x * 16 + ft];
    for (int it = 0; it < nit; it++) {
        __syncthreads();                 // prior iteration's sxn reads done
        if (tid < 256) sxn[fi][ft] = vpre;
        __syncthreads();                 // tile visible
        if (it + 1 < nit && tid < 256)   // prefetch next tile (hidden under compute)
            vpre = xn[fi * NN + blockIdx.x * 16 + (it + 1) * 16384 + ft];
        int pr = blockIdx.x * 8 + wv + it * 8192;
        int nA = pr * 2, nB = nA + 1;
        float xA = 0.f, xB = 0.f;
#pragma unroll
        for (int i = 0; i < NIN; i++) {
            float k1 = sK1[i * C + lane];
            xA = fmaf(k1, sxn[i][w2], xA);
            xB = fmaf(k1, sxn[i][w2 + 1], xB);
        }
        xA = fmaxf(xA, 0.f); xB = fmaxf(xB, 0.f);
        float uA0 = 0.f, uA1 = 0.f, uB0 = 0.f, uB1 = 0.f;
        float cA0 = 0.f, cA1 = 0.f, cB0 = 0.f, cB1 = 0.f;
#pragma unroll
        for (int p0 = 0; p0 < C; p0 += 4) {
            const float4 mu = *(const float4*)&sU[mb + (p0 ^ lx)];
            const float4 mc = *(const float4*)&sC[mb + (p0 ^ lx)];
            float a0 = RL(xA, p0 + 0), a1 = RL(xA, p0 + 1);
            float a2 = RL(xA, p0 + 2), a3 = RL(xA, p0 + 3);
            float b0 = RL(xB, p0 + 0), b1 = RL(xB, p0 + 1);
            float b2 = RL(xB, p0 + 2), b3 = RL(xB, p0 + 3);
            uA0 = fmaf(mu.x, a0, uA0); uA1 = fmaf(mu.y, a1, uA1);
            uA0 = fmaf(mu.z, a2, uA0); uA1 = fmaf(mu.w, a3, uA1);
            uB0 = fmaf(mu.x, b0, uB0); uB1 = fmaf(mu.y, b1, uB1);
            uB0 = fmaf(mu.z, b2, uB0); uB1 = fmaf(mu.w, b3, uB1);
            cA0 = fmaf(mc.x, a0, cA0); cA1 = fmaf(mc.y, a1, cA1);
            cA0 = fmaf(mc.z, a2, cA0); cA1 = fmaf(mc.w, a3, cA1);
            cB0 = fmaf(mc.x, b0, cB0); cB1 = fmaf(mc.y, b1, cB1);
            cB0 = fmaf(mc.z, b2, cB0); cB1 = fmaf(mc.w, b3, cB1);
        }
        float uA = uA0 + uA1, uB = uB0 + uB1;
        u0[(size_t)nA * C + lane] = (_Float16)uA;
        u0[(size_t)nB * C + lane] = (_Float16)uB;
        store_u8(u8, nA, lane, uA * USC);
        store_u8(u8, nB, lane, uB * USC);
        co[(size_t)nA * C + lane] = cA0 + cA1;
        co[(size_t)nB * C + lane] = cB0 + cB1;
    }
}

// ---- phase B: per-bin slot assignment into 100KB LDS image, coalesced copy-out ----
#define LADJ (NPB * SLOT)   // 25088 dwords = 100352 B LDS adjacency image
__launch_bounds__(1024)
__global__ void k_binB(const int* __restrict__ gcur, const uint32_t* __restrict__ stg,
                       unsigned* __restrict__ pk, float* __restrict__ dinv,
                       uint32_t* __restrict__ adjp) {
    __shared__ unsigned lcnt[NPB];   // low16 = slot count, high16 = j-side count
    __shared__ uint32_t ladj[LADJ];
    int b = blockIdx.x, tid = threadIdx.x;
    if (tid < NPB) lcnt[tid] = 0;
    __syncthreads();
    int cnt = gcur[b * GSTR]; if (cnt > CAP) cnt = CAP;
    int n0 = b * NPB;
    for (int k = tid; k < cnt; k += 1024) {
        uint32_t ent = stg[(size_t)b * CAP + k];
        int tl = (int)(ent >> 17);
        unsigned sign = (ent >> 16) & 1u;
        unsigned other = ent & 0xFFFFu;
        unsigned ret = atomicAdd(&lcnt[tl], 1u + (sign << 16));
        unsigned slot = ret & 0xFFFFu;
        if (slot < SLOT) ladj[(tl << 7) + slot] = other | (sign << 31);
    }
    __syncthreads();
    if (tid < NPB) {
        int n = n0 + tid;
        if (n < NN) {
            unsigned v = lcnt[tid];
            unsigned c = v & 0xFFFFu; if (c > SLOT) c = SLOT;
            unsigned deg = (v >> 16) + 1u;   // j-count + self loop
            pk[n] = (deg << 16) | c;
            dinv[n] = 1.0f / sqrtf((float)deg);
        }
    }
    // coalesced copy-out (slots >= cnt are garbage; k_weight zeroes pads)
    int nval = NN - n0; if (nval > NPB) nval = NPB; if (nval < 0) nval = 0;
    int totv = (nval << 7) >> 2;   // uint4 count
    uint4* gdst = (uint4*)(adjp + ((size_t)n0 << 7));
    const uint4* lsrc = (const uint4*)ladj;
    for (int v = tid; v < totv; v += 1024) gdst[v] = lsrc[v];
}

// ---- weight pass (uint4, 4 slots/thread): entry -> other | f16(sign*0.5*a^2)<<16 ----
// pads in [cnt,pad) zeroed; gather uses acc += |w|*d + w*|d| (== a*relu(a*d)).
__launch_bounds__(256)
__global__ void k_weight(const unsigned* __restrict__ pk, const float* __restrict__ dinv,
                         uint32_t* __restrict__ adjp) {
    int idx = blockIdx.x * 256 + threadIdx.x;   // NN*SLOT/4 threads
    int n = idx >> 5, p4 = (idx & 31) << 2;
    int cnt = (int)(pk[n] & 0xFFFFu); if (cnt > SLOT) cnt = SLOT;
    int pad = (cnt + 31) & ~31;
    if (p4 >= pad) return;
    size_t base = ((size_t)n << 7) + p4;
    uint4 e = *(const uint4*)&adjp[base];
    float dn = ASC * dinv[n];
    uint32_t r[4] = {e.x, e.y, e.z, e.w};
    uint32_t w[4];
#pragma unroll
    for (int k = 0; k < 4; k++) {
        if (p4 + k < cnt) {
            int other = (int)(r[k] & 0xFFFFu);
            float a = dn * dinv[other];
            float wv = 0.5f * a * a;
            if (r[k] >> 31) wv = -wv;
            U32H2 t; t.u = (unsigned)other; t.h.y = (_Float16)wv;
            w[k] = t.u;
        } else {
            w[k] = 0u;                           // weight 0 -> contributes nothing
        }
    }
    uint4 o; o.x = w[0]; o.y = w[1]; o.z = w[2]; o.w = w[3];
    *(uint4*)&adjp[base] = o;
}

// acc += |w|*d + w*|d|  (== a*relu(a*d)); abs() are free VOP3 source modifiers
#define ACCR(WW, QQ, A0, A1, A2, A3, U0, U1, U2, U3) {                        \
    U32H2 aw; aw.u = (WW);                                                    \
    float w_ = (float)aw.h.y;                                                 \
    f32x2 lo_ = __builtin_amdgcn_cvt_pk_f32_fp8((int)(QQ), false);            \
    f32x2 hi_ = __builtin_amdgcn_cvt_pk_f32_fp8((int)(QQ), true);             \
    float d0_ = (U0) - lo_.x, d1_ = (U1) - lo_.y;                             \
    float d2_ = (U2) - hi_.x, d3_ = (U3) - hi_.y;                             \
    A0 = fmaf(w_, __builtin_fabsf(d0_), fmaf(__builtin_fabsf(w_), d0_, A0));  \
    A1 = fmaf(w_, __builtin_fabsf(d1_), fmaf(__builtin_fabsf(w_), d1_, A1));  \
    A2 = fmaf(w_, __builtin_fabsf(d2_), fmaf(__builtin_fabsf(w_), d2_, A2));  \
    A3 = fmaf(w_, __builtin_fabsf(d3_), fmaf(__builtin_fabsf(w_), d3_, A3));  \
}

// ---- two-node interleaved gather core (broadcast scalar loads) ----
#define GATHER2_BODY(PKA, ADJP, U8R)                                          \
    uint32_t unqA = (U8R)[nA * 16 + li];                                      \
    uint32_t unqB = (U8R)[nB * 16 + li];                                      \
    f32x2 alo = __builtin_amdgcn_cvt_pk_f32_fp8((int)unqA, false);            \
    f32x2 ahi = __builtin_amdgcn_cvt_pk_f32_fp8((int)unqA, true);             \
    f32x2 blo = __builtin_amdgcn_cvt_pk_f32_fp8((int)unqB, false);            \
    f32x2 bhi = __builtin_amdgcn_cvt_pk_f32_fp8((int)unqB, true);             \
    float uA0 = alo.x, uA1 = alo.y, uA2 = ahi.x, uA3 = ahi.y;                 \
    float uB0 = blo.x, uB1 = blo.y, uB2 = bhi.x, uB3 = bhi.y;                 \
    uint2 pk2_ = *(const uint2*)&(PKA)[nA];                                   \
    int degA = (int)(pk2_.x & 0xFFFFu); if (degA > SLOT) degA = SLOT;         \
    int degB = (int)(pk2_.y & 0xFFFFu); if (degB > SLOT) degB = SLOT;         \
    int padA = (degA + 31) & ~31, padB = (degB + 31) & ~31;                   \
    int baseA = nA << 7, baseB = nB << 7;                                     \
    int maxPad = padA > padB ? padA : padB;                                   \
    float aA0 = 0.f, aA1 = 0.f, aA2 = 0.f, aA3 = 0.f;                         \
    float aB0 = 0.f, aB1 = 0.f, aB2 = 0.f, aB3 = 0.f;                         \
    for (int c0 = 0; c0 < maxPad; c0 += 32) {                                 \
        uint32_t wA[8], qA[8], wB[8], qB[8];                                  \
        bool dA = c0 < padA, dB = c0 < padB;                                  \
        if (dA) {                                                             \
            _Pragma("unroll")                                                 \
            for (int r = 0; r < 8; r++) wA[r] = (ADJP)[baseA + c0 + r * 4 + g]; \
        }                                                                     \
        if (dB) {                                                             \
            _Pragma("unroll")                                                 \
            for (int r = 0; r < 8; r++) wB[r] = (ADJP)[baseB + c0 + r * 4 + g]; \
        }                                                                     \
        if (dA) {                                                             \
            _Pragma("unroll")                                                 \
            for (int r = 0; r < 8; r++) qA[r] = (U8R)[(wA[r] & 0xFFFFu) * 16 + li]; \
        }                                                                     \
        if (dB) {                                                             \
            _Pragma("unroll")                                                 \
            for (int r = 0; r < 8; r++) qB[r] = (U8R)[(wB[r] & 0xFFFFu) * 16 + li]; \
        }                                                                     \
        if (dA) {                                                             \
            _Pragma("unroll")                                                 \
            for (int r = 0; r < 8; r++) ACCR(wA[r], qA[r], aA0, aA1, aA2, aA3, uA0, uA1, uA2, uA3) \
        }                                                                     \
        if (dB) {                                                             \
            _Pragma("unroll")                                                 \
            for (int r = 0; r < 8; r++) ACCR(wB[r], qB[r], aB0, aB1, aB2, aB3, uB0, uB1, uB2, uB3) \
        }                                                                     \
    }                                                                         \
    aA0 += __shfl_xor(aA0, 16, 64); aA0 += __shfl_xor(aA0, 32, 64);           \
    aA1 += __shfl_xor(aA1, 16, 64); aA1 += __shfl_xor(aA1, 32, 64);           \
    aA2 += __shfl_xor(aA2, 16, 64); aA2 += __shfl_xor(aA2, 32, 64);           \
    aA3 += __shfl_xor(aA3, 16, 64); aA3 += __shfl_xor(aA3, 32, 64);           \
    aB0 += __shfl_xor(aB0, 16, 64); aB0 += __shfl_xor(aB0, 32, 64);           \
    aB1 += __shfl_xor(aB1, 16, 64); aB1 += __shfl_xor(aB1, 32, 64);           \
    aB2 += __shfl_xor(aB2, 16, 64); aB2 += __shfl_xor(aB2, 32, 64);           \
    aB3 += __shfl_xor(aB3, 16, 64); aB3 += __shfl_xor(aB3, 32, 64);           \
    float rA0 = __shfl(aA0, lane >> 2, 64), rA1 = __shfl(aA1, lane >> 2, 64); \
    float rA2 = __shfl(aA2, lane >> 2, 64), rA3 = __shfl(aA3, lane >> 2, 64); \
    float rB0 = __shfl(aB0, lane >> 2, 64), rB1 = __shfl(aB1, lane >> 2, 64); \
    float rB2 = __shfl(aB2, lane >> 2, 64), rB3 = __shfl(aB3, lane >> 2, 64); \
    float sA_lane = (lane & 2) ? ((lane & 1) ? rA3 : rA2)                     \
                               : ((lane & 1) ? rA1 : rA0);                    \
    float sB_lane = (lane & 2) ? ((lane & 1) ? rB3 : rB2)                     \
                               : ((lane & 1) ? rB1 : rB0);

// transposed + XOR-swizzled M staging: sMt[(c<<6) | (p ^ ((c&7)<<2))] = M[p][c]
#define STAGE_MT(SMT, SRC) {                                                  \
    for (int idx = threadIdx.x; idx < C * C; idx += 256) {                    \
        int p_ = idx >> 6, c_ = idx & 63;                                     \
        (SMT)[(c_ << 6) | (p_ ^ ((c_ & 7) << 2))] = (SRC)[idx];               \
    }                                                                         \
}

// du[lane] = sum_p M[p][lane] * s[p] for 2 nodes; 16 ds_read_b128 + 64 RL + 64 fma per node
#define MATVEC2(SMT, SAV, SBV, DUA, DUB) {                                    \
    float mA0_ = 0.f, mA1_ = 0.f, mB0_ = 0.f, mB1_ = 0.f;                     \
    int mb_ = (lane << 6), lx_ = (lane & 7) << 2;                             \
    _Pragma("unroll")                                                         \
    for (int p0 = 0; p0 < 64; p0 += 4) {                                      \
        const float4 mv = *(const float4*)&(SMT)[mb_ + (p0 ^ lx_)];           \
        mA0_ = fmaf(mv.x, RL(SAV, p0 + 0), mA0_);                             \
        mA1_ = fmaf(mv.y, RL(SAV, p0 + 1), mA1_);                             \
        mA0_ = fmaf(mv.z, RL(SAV, p0 + 2), mA0_);                             \
        mA1_ = fmaf(mv.w, RL(SAV, p0 + 3), mA1_);                             \
        mB0_ = fmaf(mv.x, RL(SBV, p0 + 0), mB0_);                             \
        mB1_ = fmaf(mv.y, RL(SBV, p0 + 1), mB1_);                             \
        mB0_ = fmaf(mv.z, RL(SBV, p0 + 2), mB0_);                             \
        mB1_ = fmaf(mv.w, RL(SBV, p0 + 3), mB1_);                             \
    }                                                                         \
    DUA = mA0_ + mA1_; DUB = mB0_ + mB1_;                                     \
}

// ---- layers 0..2 fused: s = gather; unext = ucur - c*M2*s (f16+fp8); sacc (+)= s ----
__launch_bounds__(256, 8)
__global__ void k_gather_upd(const unsigned* __restrict__ pk, const uint32_t* __restrict__ adjp,
                             const uint32_t* __restrict__ u8r, const _Float16* __restrict__ ucur,
                             const float* __restrict__ M2s, float* __restrict__ sacc,
                             _Float16* __restrict__ unext, uint32_t* __restrict__ u8w, int beta) {
    __shared__ float sMt[C * C];
    STAGE_MT(sMt, M2s)
    __syncthreads();
    int wv = threadIdx.x >> 6, lane = threadIdx.x & 63;
    int g = lane >> 4, li = lane & 15;
    int nA = (blockIdx.x * 4 + wv) * 2;   // 6250 blocks * 4 waves * 2 nodes = 50000
    int nB = nA + 1;
    GATHER2_BODY(pk, adjp, u8r)
    float duA, duB;
    MATVEC2(sMt, sA_lane, sB_lane, duA, duB)
    float unewA = (float)ucur[(size_t)nA * C + lane] - (DTH / SDIV) * duA;
    float unewB = (float)ucur[(size_t)nB * C + lane] - (DTH / SDIV) * duB;
    unext[(size_t)nA * C + lane] = (_Float16)unewA;
    unext[(size_t)nB * C + lane] = (_Float16)unewB;
    store_u8(u8w, nA, lane, unewA * USC);
    store_u8(u8w, nB, lane, unewB * USC);
    size_t ixA = (size_t)nA * C + lane, ixB = (size_t)nB * C + lane;
    sacc[ixA] = beta ? (sacc[ixA] + sA_lane) : sA_lane;
    sacc[ixB] = beta ? (sacc[ixB] + sB_lane) : sB_lane;
}

// ---- final layer fused: stot = sacc + s; out = log_softmax(co - c*KM*stot) ----
__launch_bounds__(256, 8)
__global__ void k_gather_close(const unsigned* __restrict__ pk, const uint32_t* __restrict__ adjp,
                               const uint32_t* __restrict__ u8r, const float* __restrict__ KMs,
                               const float* __restrict__ sacc, const float* __restrict__ co,
                               float* __restrict__ out) {
    __shared__ float sKMt[C * C];
    STAGE_MT(sKMt, KMs)
    __syncthreads();
    int wv = threadIdx.x >> 6, lane = threadIdx.x & 63;
    int g = lane >> 4, li = lane & 15;
    int nA = (blockIdx.x * 4 + wv) * 2;
    int nB = nA + 1;
    GATHER2_BODY(pk, adjp, u8r)
    float stotA = sA_lane + sacc[(size_t)nA * C + lane];
    float stotB = sB_lane + sacc[(size_t)nB * C + lane];
    float dxA, dxB;
    MATVEC2(sKMt, stotA, stotB, dxA, dxB)
    float oA = co[(size_t)nA * C + lane] - (DTH / SDIV) * dxA;
    float oB = co[(size_t)nB * C + lane] - (DTH / SDIV) * dxB;
    float mA = oA, mB = oB;
#pragma unroll
    for (int off2 = 32; off2; off2 >>= 1) {
        mA = fmaxf(mA, __shfl_xor(mA, off2, 64));
        mB = fmaxf(mB, __shfl_xor(mB, off2, 64));
    }
    float sumA = expf(oA - mA), sumB = expf(oB - mB);
#pragma unroll
    for (int off2 = 32; off2; off2 >>= 1) {
        sumA += __shfl_xor(sumA, off2, 64);
        sumB += __shfl_xor(sumB, off2, 64);
    }
    out[(size_t)nA * C + lane] = oA - mA - logf(sumA);
    out[(size_t)nB * C + lane] = oB - mB - logf(sumB);
}

extern "C" void kernel_launch(void* const* d_in, const int* in_sizes, int n_in,
                              void* d_out, int out_size, void* d_ws, size_t ws_size,
                              hipStream_t stream) {
    (void)in_sizes; (void)n_in; (void)out_size; (void)ws_size;
    const float* xn   = (const float*)d_in[0];
    const int* iInd   = (const int*)d_in[1];
    const int* jInd   = (const int*)d_in[2];
    // d_in[3] = n_nodes scalar (fixed 50000)
    const float* K1   = (const float*)d_in[4];
    const float* KN1  = (const float*)d_in[5];
    const float* KNc  = (const float*)d_in[6];
    float* out = (float*)d_out;

    char* base = (char*)d_ws;
    size_t off = 0;
    auto alloc = [&](size_t bytes) { char* p = base + off; off = (off + bytes + 255) & ~(size_t)255; return p; };
    float* M2s  = (float*)alloc(C * C * 4);
    float* KMs  = (float*)alloc(C * C * 4);
    int* gcur   = (int*)alloc(NB2 * GSTR * 4);
    unsigned* pk = (unsigned*)alloc(NN * 4);
    float* dinv = (float*)alloc(NN * 4);
    float* co   = (float*)alloc((size_t)NN * C * 4);       // 12.8 MB
    float* sacc = (float*)alloc((size_t)NN * C * 4);       // 12.8 MB
    _Float16* ua = (_Float16*)alloc((size_t)NN * C * 2);   // 6.4 MB
    _Float16* ub = (_Float16*)alloc((size_t)NN * C * 2);   // 6.4 MB
    uint32_t* u8a = (uint32_t*)alloc((size_t)NN * 16 * 4); // 3.2 MB
    uint32_t* u8b = (uint32_t*)alloc((size_t)NN * 16 * 4); // 3.2 MB
    uint32_t* stg = (uint32_t*)alloc((size_t)NB2 * CAP * 4);  // 16.8 MB
    uint32_t* adjp = (uint32_t*)alloc((size_t)NN * SLOT * 4); // 25.6 MB

    // prolog: CSR build with opening matvecs fused into phase A
    k_setup<<<1, 256, 0, stream>>>(KN1, KNc, M2s, KMs, gcur);
    k_binA_open<<<ABLK, 512, 0, stream>>>(iInd, jInd, gcur, stg, xn, K1, KN1, KNc, ua, u8a, co);
    k_binB<<<NB2, 1024, 0, stream>>>(gcur, stg, pk, dinv, adjp);
    k_weight<<<(NN * SLOT / 4) / 256, 256, 0, stream>>>(pk, dinv, adjp);

    const int GB = NN / 8;    // 6250 blocks, two nodes per wave
    k_gather_upd<<<GB, 256, 0, stream>>>(pk, adjp, u8a, ua, M2s, sacc, ub, u8b, 0);
    k_gather_upd<<<GB, 256, 0, stream>>>(pk, adjp, u8b, ub, M2s, sacc, ua, u8a, 1);
    k_gather_upd<<<GB, 256, 0, stream>>>(pk, adjp, u8a, ua, M2s, sacc, ub, u8b, 1);
    k_gather_close<<<GB, 256, 0, stream>>>(pk, adjp, u8b, KMs, sacc, co, out);
}